// Round 14
// baseline (107.664 us; speedup 1.0000x reference)
//
#include <hip/hip_runtime.h>
#include <hip/hip_fp16.h>
#include <stdint.h>

// ---------------------------------------------------------------------------
// CIN block: 3 layers of out[b,k,d] = relu(sum_ij h[b,i,d] feat[b,j,d] W[k,i,j] + b[k])
// GEMM view: m=(b,d), Out[k,m] = sum_i W[k,i,:] @ (diag(h[:,i]) F)[:,m]
// R13 = R11 + CONTIGUOUS MFMA CLUSTERS (m201 discipline):
// chunk = [16 W-frag ds_reads][HLD][STAGE][build 16 B-frags (group A)]
//         [16 contiguous MFMA][build group B][16 contiguous MFMA][vmcnt+bar].
// No VALU between MFMAs inside a cluster; chains spaced 4. Rest = R11:
// 3x16KB ring, stage(q+2) in chunk q, counted vmcnt(12), wave = 64m x 32k,
// 4 indep MFMA chains, 2 blocks/CU, grid 512 = 64 mgrp x 8 kg.
// ---------------------------------------------------------------------------

typedef _Float16 half8_t __attribute__((ext_vector_type(8)));
typedef float f32x4 __attribute__((ext_vector_type(4)));
typedef float f32x16 __attribute__((ext_vector_type(16)));
typedef uint32_t u32x4 __attribute__((ext_vector_type(4)));

union H8 {
  half8_t h;
  uint32_t u[4];
  u32x4 q;
};

#define AS1 __attribute__((address_space(1)))
#define AS3 __attribute__((address_space(3)))

static __device__ __forceinline__ uint32_t pkmul(uint32_t x, uint32_t y) {
  __half2 a = __builtin_bit_cast(__half2, x);
  __half2 b = __builtin_bit_cast(__half2, y);
  __half2 r = __hmul2(a, b);
  return __builtin_bit_cast(uint32_t, r);
}

static __device__ __forceinline__ uint32_t pack2h(float a, float b) {
  __half2 r = __floats2half2_rn(a, b);
  return __builtin_bit_cast(uint32_t, r);
}

// ---- fused prep -------------------------------------------------------------
// W [k][i][j] f32 -> Wt chunks [i][kt][g*16+kr][8 f16]; thread = (k,i,j-octet)
// blocks [0,128): W0 ; [128,640): W1 ; [640,1152): W2
// blocks [1152,1216): feat -> F16 [m][32 j] f16, hP0 [mb][4 g8][4 iw][32 m]
__global__ void prep_kernel(const float* __restrict__ W0, const float* __restrict__ W1,
                            const float* __restrict__ W2, const float* __restrict__ feat,
                            uint16_t* __restrict__ Wt0, uint16_t* __restrict__ Wt1,
                            uint16_t* __restrict__ Wt2,
                            uint16_t* __restrict__ F16, uint32_t* __restrict__ hP0) {
  int blk = blockIdx.x;
  if (blk < 1152) {
    const float* W; uint16_t* Wt; int FLsh, base;
    if (blk < 128)      { W = W0; Wt = Wt0; FLsh = 5; base = 0; }
    else if (blk < 640) { W = W1; Wt = Wt1; FLsh = 7; base = 128; }
    else                { W = W2; Wt = Wt2; FLsh = 7; base = 640; }
    int idx4 = (blk - base) * 256 + threadIdx.x;
    int jg = idx4 & 3;
    int i = (idx4 >> 2) & ((1 << FLsh) - 1);
    int k = idx4 >> (2 + FLsh);
    const float* src = W + ((size_t)(k << FLsh) + i) * 32 + jg * 8;
    float4 x0 = *(const float4*)(src);
    float4 x1 = *(const float4*)(src + 4);
    u32x4 o;
    o[0] = pack2h(x0.x, x0.y);
    o[1] = pack2h(x0.z, x0.w);
    o[2] = pack2h(x1.x, x1.y);
    o[3] = pack2h(x1.z, x1.w);
    int kr = k & 15, kt = k >> 4;
    *(u32x4*)((uint32_t*)Wt + (((size_t)i * 16 + kt) * 64 + jg * 16 + kr) * 4) = o;
  } else {
    int m = (blk - 1152) * 256 + threadIdx.x;  // 0..16383
    int b = m >> 5, d = m & 31;
    const float* fb = feat + (size_t)b * 1024 + d;
    uint16_t hs[32];
#pragma unroll
    for (int j = 0; j < 32; ++j)
      hs[j] = __half_as_ushort(__float2half(fb[j * 32]));
    // hP0 [mb][g8][iw][32 m]: pair jp -> (hs[2jp], hs[2jp+1])
    int mb = m >> 5, ml = m & 31;
#pragma unroll
    for (int jp = 0; jp < 16; ++jp) {
      uint32_t pr = (uint32_t)hs[2 * jp] | ((uint32_t)hs[2 * jp + 1] << 16);
      hP0[((size_t)(mb * 4 + (jp >> 2)) * 4 + (jp & 3)) * 32 + ml] = pr;
    }
#pragma unroll
    for (int c = 0; c < 4; ++c) {
      u32x4 q;
      q[0] = (uint32_t)hs[c * 8 + 0] | ((uint32_t)hs[c * 8 + 1] << 16);
      q[1] = (uint32_t)hs[c * 8 + 2] | ((uint32_t)hs[c * 8 + 3] << 16);
      q[2] = (uint32_t)hs[c * 8 + 4] | ((uint32_t)hs[c * 8 + 5] << 16);
      q[3] = (uint32_t)hs[c * 8 + 6] | ((uint32_t)hs[c * 8 + 7] << 16);
      *(u32x4*)(F16 + (size_t)m * 32 + c * 8) = q;
    }
  }
}

// ---- fused CIN layer GEMM ---------------------------------------------------
// grid 512: bx = mgrp*8 + kg. Block 256 thr (4 waves); wave w covers
// mb0 = mgrp*8 + w*2 and mb0+1 (64 m) x 32 k (kg), full K. 32x32x16 MFMA.
template <int FL>
__global__ __launch_bounds__(256, 2) void gemm_cin(
    const uint32_t* __restrict__ hP,    // [mb][FL/8 g8][4 iw][32 m] u32 pairs
    const uint16_t* __restrict__ wt,    // [FL][16 kt][64][8] f16 chunks
    const uint16_t* __restrict__ f16m,  // [16384][32] f16
    const float* __restrict__ bias,     // [256]
    uint32_t* __restrict__ houtP,       // [mb][16 g8][4 iw][32 m], or null
    float* __restrict__ outp,           // [512][512] f32
    int obase, int klo) {
  constexpr int NCHK = FL / 8;    // chunks of 8 i-slices (16KB)
  constexpr int NCM = NCHK - 1;   // power-of-2 mask
  __shared__ __align__(16) char smem[49152];  // 3 x 16KB ring
  const int tid = threadIdx.x;
  const int lane = tid & 63, w = tid >> 6;
  const int l31 = lane & 31, l5 = lane >> 5;
  const int kg = blockIdx.x & 7, mgrp = blockIdx.x >> 3;
  const int mb0 = mgrp * 8 + w * 2;

  // --- resident F fragments (issued first -> oldest in vmcnt queue) ---
  const uint16_t* fb0 = f16m + (size_t)(mb0 * 32 + l31) * 32 + l5 * 8;
  H8 ffA0, ffA1, ffB0, ffB1;
  ffA0.q = *(const u32x4*)(fb0);
  ffA1.q = *(const u32x4*)(fb0 + 16);
  ffB0.q = *(const u32x4*)(fb0 + 1024);
  ffB1.q = *(const u32x4*)(fb0 + 1040);

  // --- W staging: chunk = 8 i x 2KB (kt pair of kg); 4 glds/wave/chunk ---
  const char* wsrc = (const char*)wt + kg * 2048 + (size_t)(tid >> 7) * 16384 +
                     (tid & 127) * 16;
  char* sdst = smem + tid * 16;

#define STAGE(QQ, BUFOFF)                                                     \
  { const char* s_ = wsrc + (size_t)((QQ) & NCM) * 131072;                    \
    char* d_ = sdst + (BUFOFF);                                               \
    _Pragma("unroll") for (int c_ = 0; c_ < 4; ++c_)                          \
      __builtin_amdgcn_global_load_lds(                                       \
          (const AS1 uint32_t*)(s_ + c_ * 32768),                             \
          (AS3 uint32_t*)(d_ + c_ * 4096), 16, 0, 0); }

  // --- h pair streams (per chunk: 4 iw dwords per mb, coalesced) ---
  const uint32_t* hbA = hP + (size_t)mb0 * (FL / 8) * 128 + l31;
  const uint32_t* hbB = hbA + (size_t)(FL / 8) * 128;

#define HLD(QQ, DA, DB)                                                       \
  { const uint32_t* pa_ = hbA + ((QQ) & NCM) * 128;                           \
    const uint32_t* pb_ = hbB + ((QQ) & NCM) * 128;                           \
    DA[0] = pa_[0]; DA[1] = pa_[32]; DA[2] = pa_[64]; DA[3] = pa_[96];        \
    DB[0] = pb_[0]; DB[1] = pb_[32]; DB[2] = pb_[64]; DB[3] = pb_[96]; }

  u32x4 hcA, hcB, hnA, hnB;

  // --- prologue: S(0), S(1), H(0); counted wait for S(0) ---
  STAGE(0, 0)
  STAGE(1, 16384)
  HLD(0, hcA, hcB)

  f32x16 accA0 = {}, accA1 = {}, accB0 = {}, accB1 = {};
  const char* rbase = smem + ((l31 >> 4) << 10) + (l5 << 8) + ((lane & 15) << 4);

  asm volatile("s_waitcnt vmcnt(12)" ::: "memory");  // ff+S(0) retired
  __builtin_amdgcn_s_barrier();

  // Build 4 B-frags for one i-step (16 pkmul + 2 perm), NO MFMA here.
#define BSTEP(HA_, HB_, PSEL, BA0, BA1, BB0, BB1)                             \
  { uint32_t eA_ = __builtin_amdgcn_perm((HA_), (HA_), (PSEL));               \
    uint32_t eB_ = __builtin_amdgcn_perm((HB_), (HB_), (PSEL));               \
    _Pragma("unroll") for (int c_ = 0; c_ < 4; ++c_) {                        \
      BA0.u[c_] = pkmul(ffA0.u[c_], eA_);                                     \
      BA1.u[c_] = pkmul(ffA1.u[c_], eA_);                                     \
      BB0.u[c_] = pkmul(ffB0.u[c_], eB_);                                     \
      BB1.u[c_] = pkmul(ffB1.u[c_], eB_);                                     \
    } }

  // 4 MFMA for one i-step (chains A0,B0,A1,B1 -> same-chain spacing 4).
#define MQUAD(WE, WO, BA0, BA1, BB0, BB1)                                         \
  accA0 = __builtin_amdgcn_mfma_f32_32x32x16_f16((WE).h, BA0.h, accA0, 0, 0, 0);  \
  accB0 = __builtin_amdgcn_mfma_f32_32x32x16_f16((WE).h, BB0.h, accB0, 0, 0, 0);  \
  accA1 = __builtin_amdgcn_mfma_f32_32x32x16_f16((WO).h, BA1.h, accA1, 0, 0, 0);  \
  accB1 = __builtin_amdgcn_mfma_f32_32x32x16_f16((WO).h, BB1.h, accB1, 0, 0, 0);

#define CHUNK(QQ, RDOFF, STOFF, HCA_, HCB_, HNA_, HNB_)                           \
  { const char* rb_ = rbase + (RDOFF);                                            \
    H8 w0, w1, w2, w3, w4, w5, w6, w7, w8, w9, wa, wb, wc, wd, we, wf;            \
    w0.q = *(const u32x4*)(rb_ + 0 * 2048);                                       \
    w1.q = *(const u32x4*)(rb_ + 0 * 2048 + 512);                                 \
    w2.q = *(const u32x4*)(rb_ + 1 * 2048);                                       \
    w3.q = *(const u32x4*)(rb_ + 1 * 2048 + 512);                                 \
    w4.q = *(const u32x4*)(rb_ + 2 * 2048);                                       \
    w5.q = *(const u32x4*)(rb_ + 2 * 2048 + 512);                                 \
    w6.q = *(const u32x4*)(rb_ + 3 * 2048);                                       \
    w7.q = *(const u32x4*)(rb_ + 3 * 2048 + 512);                                 \
    w8.q = *(const u32x4*)(rb_ + 4 * 2048);                                       \
    w9.q = *(const u32x4*)(rb_ + 4 * 2048 + 512);                                 \
    wa.q = *(const u32x4*)(rb_ + 5 * 2048);                                       \
    wb.q = *(const u32x4*)(rb_ + 5 * 2048 + 512);                                 \
    wc.q = *(const u32x4*)(rb_ + 6 * 2048);                                       \
    wd.q = *(const u32x4*)(rb_ + 6 * 2048 + 512);                                 \
    we.q = *(const u32x4*)(rb_ + 7 * 2048);                                       \
    wf.q = *(const u32x4*)(rb_ + 7 * 2048 + 512);                                 \
    HLD((QQ) + 1, HNA_, HNB_)                                                     \
    STAGE((QQ) + 2, STOFF)                                                        \
    /* group A: steps 0-3 -> build 16 frags, then 16 contiguous MFMA */           \
    { H8 pA0_0, pA1_0, pB0_0, pB1_0, pA0_1, pA1_1, pB0_1, pB1_1;                  \
      H8 pA0_2, pA1_2, pB0_2, pB1_2, pA0_3, pA1_3, pB0_3, pB1_3;                  \
      BSTEP(HCA_[0], HCB_[0], 0x01000100u, pA0_0, pA1_0, pB0_0, pB1_0)            \
      BSTEP(HCA_[0], HCB_[0], 0x03020302u, pA0_1, pA1_1, pB0_1, pB1_1)            \
      BSTEP(HCA_[1], HCB_[1], 0x01000100u, pA0_2, pA1_2, pB0_2, pB1_2)            \
      BSTEP(HCA_[1], HCB_[1], 0x03020302u, pA0_3, pA1_3, pB0_3, pB1_3)            \
      __builtin_amdgcn_s_setprio(1);                                              \
      MQUAD(w0, w1, pA0_0, pA1_0, pB0_0, pB1_0)                                   \
      MQUAD(w2, w3, pA0_1, pA1_1, pB0_1, pB1_1)                                   \
      MQUAD(w4, w5, pA0_2, pA1_2, pB0_2, pB1_2)                                   \
      MQUAD(w6, w7, pA0_3, pA1_3, pB0_3, pB1_3)                                   \
      __builtin_amdgcn_s_setprio(0); }                                            \
    /* group B: steps 4-7 */                                                      \
    { H8 pA0_0, pA1_0, pB0_0, pB1_0, pA0_1, pA1_1, pB0_1, pB1_1;                  \
      H8 pA0_2, pA1_2, pB0_2, pB1_2, pA0_3, pA1_3, pB0_3, pB1_3;                  \
      BSTEP(HCA_[2], HCB_[2], 0x01000100u, pA0_0, pA1_0, pB0_0, pB1_0)            \
      BSTEP(HCA_[2], HCB_[2], 0x03020302u, pA0_1, pA1_1, pB0_1, pB1_1)            \
      BSTEP(HCA_[3], HCB_[3], 0x01000100u, pA0_2, pA1_2, pB0_2, pB1_2)            \
      BSTEP(HCA_[3], HCB_[3], 0x03020302u, pA0_3, pA1_3, pB0_3, pB1_3)            \
      __builtin_amdgcn_s_setprio(1);                                              \
      MQUAD(w8, w9, pA0_0, pA1_0, pB0_0, pB1_0)                                   \
      MQUAD(wa, wb, pA0_1, pA1_1, pB0_1, pB1_1)                                   \
      MQUAD(wc, wd, pA0_2, pA1_2, pB0_2, pB1_2)                                   \
      MQUAD(we, wf, pA0_3, pA1_3, pB0_3, pB1_3)                                   \
      __builtin_amdgcn_s_setprio(0); }                                            \
    asm volatile("s_waitcnt vmcnt(12)" ::: "memory");                             \
    __builtin_amdgcn_s_barrier();                                                 \
  }

  int r0 = 0, r1 = 16384, r2 = 32768;
#pragma unroll 1
  for (int q = 0; q < NCHK; q += 2) {
    CHUNK(q, r0, r2, hcA, hcB, hnA, hnB)
    CHUNK(q + 1, r1, r0, hnA, hnB, hcA, hcB)
    int t = r2; r2 = r1; r1 = r0; r0 = t;
  }
#undef CHUNK
#undef MQUAD
#undef BSTEP
#undef STAGE
#undef HLD

  asm volatile("s_waitcnt vmcnt(0)" ::: "memory");  // drain wrapped tail stages

  // ---- epilogue: sum j-half chains, bias+relu; row k = 8a+4*l5+t, col m=l31 --
  f32x16 accA = accA0 + accA1;
  f32x16 accB = accB0 + accB1;
  f32x4 bv[4];
#pragma unroll
  for (int a = 0; a < 4; ++a)
    bv[a] = *(const f32x4*)(bias + kg * 32 + a * 8 + l5 * 4);

#define EPILOG(ACC, MB)                                                           \
  {                                                                               \
    float v[16];                                                                  \
    _Pragma("unroll") for (int a = 0; a < 4; ++a)                                 \
        _Pragma("unroll") for (int t = 0; t < 4; ++t) {                           \
      float x = ACC[a * 4 + t] + bv[a][t];                                        \
      v[a * 4 + t] = x > 0.f ? x : 0.f;                                           \
    }                                                                             \
    if (houtP != nullptr && kg < 4) {                                             \
      _Pragma("unroll") for (int a = 0; a < 4; ++a)                               \
          _Pragma("unroll") for (int c = 0; c < 2; ++c) {                         \
        uint32_t pr = pack2h(v[a * 4 + 2 * c], v[a * 4 + 2 * c + 1]);             \
        houtP[((size_t)((MB) * 16 + kg * 4 + a) * 4 + 2 * l5 + c) * 32 + l31] =   \
            pr;                                                                   \
      }                                                                           \
    }                                                                             \
    _Pragma("unroll") for (int r = 0; r < 16; ++r) {                              \
      float x = v[r];                                                             \
      x += __shfl_xor(x, 1); x += __shfl_xor(x, 2);                               \
      x += __shfl_xor(x, 4); x += __shfl_xor(x, 8);                               \
      x += __shfl_xor(x, 16);                                                     \
      v[r] = x;                                                                   \
    }                                                                             \
    if (kg * 32 >= klo && (lane == 0 || lane == 32)) {                            \
      float* ob = outp + (size_t)(MB) * 512 + obase + kg * 32 - klo + l5 * 4;     \
      _Pragma("unroll") for (int a = 0; a < 4; ++a)                               \
          *(f32x4*)(ob + a * 8) =                                                 \
              (f32x4){v[a * 4], v[a * 4 + 1], v[a * 4 + 2], v[a * 4 + 3]};        \
    }                                                                             \
  }

  EPILOG(accA, mb0)
  EPILOG(accB, mb0 + 1)
#undef EPILOG
}

// ---------------------------------------------------------------------------
extern "C" void kernel_launch(void* const* d_in, const int* in_sizes, int n_in,
                              void* d_out, int out_size, void* d_ws, size_t ws_size,
                              hipStream_t stream) {
  const float* feat = (const float*)d_in[0];
  const float* W0 = (const float*)d_in[1];
  const float* b0 = (const float*)d_in[2];
  const float* W1 = (const float*)d_in[3];
  const float* b1 = (const float*)d_in[4];
  const float* W2 = (const float*)d_in[5];
  const float* b2 = (const float*)d_in[6];
  float* out = (float*)d_out;
  char* ws = (char*)d_ws;

  // workspace layout (bytes)
  uint16_t* Wt0 = (uint16_t*)(ws + 0x000000);  // 512KB
  uint16_t* Wt1 = (uint16_t*)(ws + 0x080000);  // 2MB
  uint16_t* Wt2 = (uint16_t*)(ws + 0x280000);  // 2MB
  uint16_t* F16 = (uint16_t*)(ws + 0x480000);  // 1MB
  uint32_t* hP0 = (uint32_t*)(ws + 0x580000);  // [512][4][4][32]  u32 = 1MB
  uint32_t* hP1 = (uint32_t*)(ws + 0x680000);  // [512][16][4][32] u32 = 4MB
  uint32_t* hP2 = (uint32_t*)(ws + 0xA80000);  // 4MB (end 14.5MB)

  prep_kernel<<<1216, 256, 0, stream>>>(W0, W1, W2, feat, Wt0, Wt1, Wt2, F16, hP0);

  // layers: out cols [0,128)=L0 k>=128, [128,256)=L1 k>=128, [256,512)=L2 all k
  gemm_cin<32><<<512, 256, 0, stream>>>(hP0, Wt0, F16, b0, hP1, out, 0, 128);
  gemm_cin<128><<<512, 256, 0, stream>>>(hP1, Wt1, F16, b1, hP2, out, 128, 128);
  gemm_cin<128><<<512, 256, 0, stream>>>(hP2, Wt2, F16, b2, (uint32_t*)nullptr,
                                         out, 256, 0);
}

// Round 15
// 106.533 us; speedup vs baseline: 1.0106x; 1.0106x over previous
//
#include <hip/hip_runtime.h>
#include <hip/hip_fp16.h>
#include <stdint.h>

// ---------------------------------------------------------------------------
// CIN block: 3 layers of out[b,k,d] = relu(sum_ij h[b,i,d] feat[b,j,d] W[k,i,j] + b[k])
// GEMM view: m=(b,d), Out[k,m] = sum_i W[k,i,:] @ (diag(h[:,i]) F)[:,m]
// R14 = R11 + m201-style PHASE-LOCKED schedule:
// chunk (8 i) = 2 phases; each phase = [pre-stage NEXT phase: 8 ds_reads,
// B-builds, HLD/STAGE] [barrier] [16-MFMA cluster (B-builds for remaining
// steps between its 8-MFMA halves)] [barrier]. Counted vmcnt(20) once per
// chunk (retires stage(q+1) exactly; no in-loop drain). Waves phase-lock so
// LDS unit and matrix pipe alternate instead of colliding per-chunk.
// Rest = R11: 3x16KB ring, wave = 64m x 32k (2 mb), grid 512 = 64mgrp x 8kg,
// 2 blocks/CU, merged 2-chain accumulators (chain-split proven irrelevant).
// ---------------------------------------------------------------------------

typedef _Float16 half8_t __attribute__((ext_vector_type(8)));
typedef float f32x4 __attribute__((ext_vector_type(4)));
typedef float f32x16 __attribute__((ext_vector_type(16)));
typedef uint32_t u32x4 __attribute__((ext_vector_type(4)));

union H8 {
  half8_t h;
  uint32_t u[4];
  u32x4 q;
};

#define AS1 __attribute__((address_space(1)))
#define AS3 __attribute__((address_space(3)))

static __device__ __forceinline__ uint32_t pkmul(uint32_t x, uint32_t y) {
  __half2 a = __builtin_bit_cast(__half2, x);
  __half2 b = __builtin_bit_cast(__half2, y);
  __half2 r = __hmul2(a, b);
  return __builtin_bit_cast(uint32_t, r);
}

static __device__ __forceinline__ uint32_t pack2h(float a, float b) {
  __half2 r = __floats2half2_rn(a, b);
  return __builtin_bit_cast(uint32_t, r);
}

// ---- fused prep (unchanged from R11) ----------------------------------------
__global__ void prep_kernel(const float* __restrict__ W0, const float* __restrict__ W1,
                            const float* __restrict__ W2, const float* __restrict__ feat,
                            uint16_t* __restrict__ Wt0, uint16_t* __restrict__ Wt1,
                            uint16_t* __restrict__ Wt2,
                            uint16_t* __restrict__ F16, uint32_t* __restrict__ hP0) {
  int blk = blockIdx.x;
  if (blk < 1152) {
    const float* W; uint16_t* Wt; int FLsh, base;
    if (blk < 128)      { W = W0; Wt = Wt0; FLsh = 5; base = 0; }
    else if (blk < 640) { W = W1; Wt = Wt1; FLsh = 7; base = 128; }
    else                { W = W2; Wt = Wt2; FLsh = 7; base = 640; }
    int idx4 = (blk - base) * 256 + threadIdx.x;
    int jg = idx4 & 3;
    int i = (idx4 >> 2) & ((1 << FLsh) - 1);
    int k = idx4 >> (2 + FLsh);
    const float* src = W + ((size_t)(k << FLsh) + i) * 32 + jg * 8;
    float4 x0 = *(const float4*)(src);
    float4 x1 = *(const float4*)(src + 4);
    u32x4 o;
    o[0] = pack2h(x0.x, x0.y);
    o[1] = pack2h(x0.z, x0.w);
    o[2] = pack2h(x1.x, x1.y);
    o[3] = pack2h(x1.z, x1.w);
    int kr = k & 15, kt = k >> 4;
    *(u32x4*)((uint32_t*)Wt + (((size_t)i * 16 + kt) * 64 + jg * 16 + kr) * 4) = o;
  } else {
    int m = (blk - 1152) * 256 + threadIdx.x;  // 0..16383
    int b = m >> 5, d = m & 31;
    const float* fb = feat + (size_t)b * 1024 + d;
    uint16_t hs[32];
#pragma unroll
    for (int j = 0; j < 32; ++j)
      hs[j] = __half_as_ushort(__float2half(fb[j * 32]));
    int mb = m >> 5, ml = m & 31;
#pragma unroll
    for (int jp = 0; jp < 16; ++jp) {
      uint32_t pr = (uint32_t)hs[2 * jp] | ((uint32_t)hs[2 * jp + 1] << 16);
      hP0[((size_t)(mb * 4 + (jp >> 2)) * 4 + (jp & 3)) * 32 + ml] = pr;
    }
#pragma unroll
    for (int c = 0; c < 4; ++c) {
      u32x4 q;
      q[0] = (uint32_t)hs[c * 8 + 0] | ((uint32_t)hs[c * 8 + 1] << 16);
      q[1] = (uint32_t)hs[c * 8 + 2] | ((uint32_t)hs[c * 8 + 3] << 16);
      q[2] = (uint32_t)hs[c * 8 + 4] | ((uint32_t)hs[c * 8 + 5] << 16);
      q[3] = (uint32_t)hs[c * 8 + 6] | ((uint32_t)hs[c * 8 + 7] << 16);
      *(u32x4*)(F16 + (size_t)m * 32 + c * 8) = q;
    }
  }
}

// ---- fused CIN layer GEMM ---------------------------------------------------
template <int FL>
__global__ __launch_bounds__(256, 2) void gemm_cin(
    const uint32_t* __restrict__ hP,    // [mb][FL/8 g8][4 iw][32 m] u32 pairs
    const uint16_t* __restrict__ wt,    // [FL][16 kt][64][8] f16 chunks
    const uint16_t* __restrict__ f16m,  // [16384][32] f16
    const float* __restrict__ bias,     // [256]
    uint32_t* __restrict__ houtP,       // [mb][16 g8][4 iw][32 m], or null
    float* __restrict__ outp,           // [512][512] f32
    int obase, int klo) {
  constexpr int NCHK = FL / 8;
  constexpr int NCM = NCHK - 1;
  __shared__ __align__(16) char smem[49152];  // 3 x 16KB ring
  const int tid = threadIdx.x;
  const int lane = tid & 63, w = tid >> 6;
  const int l31 = lane & 31, l5 = lane >> 5;
  const int kg = blockIdx.x & 7, mgrp = blockIdx.x >> 3;
  const int mb0 = mgrp * 8 + w * 2;

  // --- resident F fragments ---
  const uint16_t* fb0 = f16m + (size_t)(mb0 * 32 + l31) * 32 + l5 * 8;
  H8 ffA0, ffA1, ffB0, ffB1;
  ffA0.q = *(const u32x4*)(fb0);
  ffA1.q = *(const u32x4*)(fb0 + 16);
  ffB0.q = *(const u32x4*)(fb0 + 1024);
  ffB1.q = *(const u32x4*)(fb0 + 1040);

  // --- W staging: chunk = 8 i x 2KB (kt pair of kg); 4 glds/wave/chunk ---
  const char* wsrc = (const char*)wt + kg * 2048 + (size_t)(tid >> 7) * 16384 +
                     (tid & 127) * 16;
  char* sdst = smem + tid * 16;

#define STAGE(QQ, BUFOFF)                                                     \
  { const char* s_ = wsrc + (size_t)((QQ) & NCM) * 131072;                    \
    char* d_ = sdst + (BUFOFF);                                               \
    _Pragma("unroll") for (int c_ = 0; c_ < 4; ++c_)                          \
      __builtin_amdgcn_global_load_lds(                                       \
          (const AS1 uint32_t*)(s_ + c_ * 32768),                             \
          (AS3 uint32_t*)(d_ + c_ * 4096), 16, 0, 0); }

  const uint32_t* hbA = hP + (size_t)mb0 * (FL / 8) * 128 + l31;
  const uint32_t* hbB = hbA + (size_t)(FL / 8) * 128;

#define HLD(QQ, DA, DB)                                                       \
  { const uint32_t* pa_ = hbA + ((QQ) & NCM) * 128;                           \
    const uint32_t* pb_ = hbB + ((QQ) & NCM) * 128;                           \
    DA[0] = pa_[0]; DA[1] = pa_[32]; DA[2] = pa_[64]; DA[3] = pa_[96];        \
    DB[0] = pb_[0]; DB[1] = pb_[32]; DB[2] = pb_[64]; DB[3] = pb_[96]; }

  u32x4 hcA, hcB, hnA, hnB;

  // --- prologue: S(0), S(1), H(0); full drain once; prime wa + pa ---
  STAGE(0, 0)
  STAGE(1, 16384)
  HLD(0, hcA, hcB)

  f32x16 accA = {}, accB = {};
  const char* rbase = smem + ((l31 >> 4) << 10) + (l5 << 8) + ((lane & 15) << 4);

  asm volatile("s_waitcnt vmcnt(0)" ::: "memory");
  __builtin_amdgcn_s_barrier();

  // B-build for one i-step: 2 perm + 16 pkmul -> 4 frags
#define BSTEP(HA_, HB_, PSEL, BA0, BA1, BB0, BB1)                             \
  { uint32_t eA_ = __builtin_amdgcn_perm((HA_), (HA_), (PSEL));               \
    uint32_t eB_ = __builtin_amdgcn_perm((HB_), (HB_), (PSEL));               \
    _Pragma("unroll") for (int c_ = 0; c_ < 4; ++c_) {                        \
      BA0.u[c_] = pkmul(ffA0.u[c_], eA_);                                     \
      BA1.u[c_] = pkmul(ffA1.u[c_], eA_);                                     \
      BB0.u[c_] = pkmul(ffB0.u[c_], eB_);                                     \
      BB1.u[c_] = pkmul(ffB1.u[c_], eB_);                                     \
    } }

  // 4 MFMA for one i-step (2 chains, spacing 2 — proven irrelevant in R11)
#define MQUAD(WE, WO, BA0, BA1, BB0, BB1)                                        \
  accA = __builtin_amdgcn_mfma_f32_32x32x16_f16((WE).h, BA0.h, accA, 0, 0, 0);   \
  accB = __builtin_amdgcn_mfma_f32_32x32x16_f16((WE).h, BB0.h, accB, 0, 0, 0);   \
  accA = __builtin_amdgcn_mfma_f32_32x32x16_f16((WO).h, BA1.h, accA, 0, 0, 0);   \
  accB = __builtin_amdgcn_mfma_f32_32x32x16_f16((WO).h, BB1.h, accB, 0, 0, 0);

  // loop-carried operand banks
  H8 wa0, wa1, wa2, wa3, wa4, wa5, wa6, wa7;  // phase-A W (steps 0-3)
  H8 wb0, wb1, wb2, wb3, wb4, wb5, wb6, wb7;  // phase-B W (steps 4-7)
  H8 pa00, pa01, pa02, pa03, pa10, pa11, pa12, pa13;  // phase-A B-frags
  H8 pa20, pa21, pa22, pa23, pa30, pa31, pa32, pa33;
  H8 pb00, pb01, pb02, pb03, pb10, pb11, pb12, pb13;  // phase-B B-frags
  H8 pb20, pb21, pb22, pb23, pb30, pb31, pb32, pb33;

  // prime chunk 0 phase A: W frags (buf0, steps 0-3) + B frags (h(0))
  {
    const char* rb_ = rbase;
    wa0.q = *(const u32x4*)(rb_ + 0 * 2048);
    wa1.q = *(const u32x4*)(rb_ + 0 * 2048 + 512);
    wa2.q = *(const u32x4*)(rb_ + 1 * 2048);
    wa3.q = *(const u32x4*)(rb_ + 1 * 2048 + 512);
    wa4.q = *(const u32x4*)(rb_ + 2 * 2048);
    wa5.q = *(const u32x4*)(rb_ + 2 * 2048 + 512);
    wa6.q = *(const u32x4*)(rb_ + 3 * 2048);
    wa7.q = *(const u32x4*)(rb_ + 3 * 2048 + 512);
    BSTEP(hcA[0], hcB[0], 0x01000100u, pa00, pa01, pa02, pa03)
    BSTEP(hcA[0], hcB[0], 0x03020302u, pa10, pa11, pa12, pa13)
    BSTEP(hcA[1], hcB[1], 0x01000100u, pa20, pa21, pa22, pa23)
    BSTEP(hcA[1], hcB[1], 0x03020302u, pa30, pa31, pa32, pa33)
  }

  int c0 = 0, c1 = 16384, c2 = 32768;
#pragma unroll 1
  for (int q = 0; q < NCHK; ++q) {
    // ======== PHASE A: MFMA steps 0-3; pre-stage phase B ========
    {
      const char* rb_ = rbase + c0;
      wb0.q = *(const u32x4*)(rb_ + 4 * 2048);
      wb1.q = *(const u32x4*)(rb_ + 4 * 2048 + 512);
      wb2.q = *(const u32x4*)(rb_ + 5 * 2048);
      wb3.q = *(const u32x4*)(rb_ + 5 * 2048 + 512);
      wb4.q = *(const u32x4*)(rb_ + 6 * 2048);
      wb5.q = *(const u32x4*)(rb_ + 6 * 2048 + 512);
      wb6.q = *(const u32x4*)(rb_ + 7 * 2048);
      wb7.q = *(const u32x4*)(rb_ + 7 * 2048 + 512);
      HLD(q + 1, hnA, hnB)
      BSTEP(hcA[2], hcB[2], 0x01000100u, pb00, pb01, pb02, pb03)
      BSTEP(hcA[2], hcB[2], 0x03020302u, pb10, pb11, pb12, pb13)
      __builtin_amdgcn_s_barrier();
      __builtin_amdgcn_s_setprio(1);
      MQUAD(wa0, wa1, pa00, pa01, pa02, pa03)
      MQUAD(wa2, wa3, pa10, pa11, pa12, pa13)
      __builtin_amdgcn_s_setprio(0);
      BSTEP(hcA[3], hcB[3], 0x01000100u, pb20, pb21, pb22, pb23)
      BSTEP(hcA[3], hcB[3], 0x03020302u, pb30, pb31, pb32, pb33)
      __builtin_amdgcn_s_setprio(1);
      MQUAD(wa4, wa5, pa20, pa21, pa22, pa23)
      MQUAD(wa6, wa7, pa30, pa31, pa32, pa33)
      __builtin_amdgcn_s_setprio(0);
      __builtin_amdgcn_s_barrier();
    }
    // ======== PHASE B: MFMA steps 4-7; pre-stage next chunk phase A ========
    {
      STAGE(q + 2, c2)
      asm volatile("s_waitcnt vmcnt(20)" ::: "memory");  // stage(q+1) landed
      __builtin_amdgcn_s_barrier();
      const char* rb_ = rbase + c1;
      wa0.q = *(const u32x4*)(rb_ + 0 * 2048);
      wa1.q = *(const u32x4*)(rb_ + 0 * 2048 + 512);
      wa2.q = *(const u32x4*)(rb_ + 1 * 2048);
      wa3.q = *(const u32x4*)(rb_ + 1 * 2048 + 512);
      wa4.q = *(const u32x4*)(rb_ + 2 * 2048);
      wa5.q = *(const u32x4*)(rb_ + 2 * 2048 + 512);
      wa6.q = *(const u32x4*)(rb_ + 3 * 2048);
      wa7.q = *(const u32x4*)(rb_ + 3 * 2048 + 512);
      BSTEP(hnA[0], hnB[0], 0x01000100u, pa00, pa01, pa02, pa03)
      BSTEP(hnA[0], hnB[0], 0x03020302u, pa10, pa11, pa12, pa13)
      __builtin_amdgcn_s_setprio(1);
      MQUAD(wb0, wb1, pb00, pb01, pb02, pb03)
      MQUAD(wb2, wb3, pb10, pb11, pb12, pb13)
      __builtin_amdgcn_s_setprio(0);
      BSTEP(hnA[1], hnB[1], 0x01000100u, pa20, pa21, pa22, pa23)
      BSTEP(hnA[1], hnB[1], 0x03020302u, pa30, pa31, pa32, pa33)
      __builtin_amdgcn_s_setprio(1);
      MQUAD(wb4, wb5, pb20, pb21, pb22, pb23)
      MQUAD(wb6, wb7, pb30, pb31, pb32, pb33)
      __builtin_amdgcn_s_setprio(0);
      __builtin_amdgcn_s_barrier();
    }
    hcA = hnA; hcB = hnB;
    int t = c0; c0 = c1; c1 = c2; c2 = t;
  }
#undef MQUAD
#undef BSTEP
#undef STAGE
#undef HLD

  asm volatile("s_waitcnt vmcnt(0)" ::: "memory");  // drain wrapped tail stages

  // ---- epilogue: bias+relu; C row k = 8a+4*l5+t, col m = l31 -----------------
  f32x4 bv[4];
#pragma unroll
  for (int a = 0; a < 4; ++a)
    bv[a] = *(const f32x4*)(bias + kg * 32 + a * 8 + l5 * 4);

#define EPILOG(ACC, MB)                                                           \
  {                                                                               \
    float v[16];                                                                  \
    _Pragma("unroll") for (int a = 0; a < 4; ++a)                                 \
        _Pragma("unroll") for (int t = 0; t < 4; ++t) {                           \
      float x = ACC[a * 4 + t] + bv[a][t];                                        \
      v[a * 4 + t] = x > 0.f ? x : 0.f;                                           \
    }                                                                             \
    if (houtP != nullptr && kg < 4) {                                             \
      _Pragma("unroll") for (int a = 0; a < 4; ++a)                               \
          _Pragma("unroll") for (int c = 0; c < 2; ++c) {                         \
        uint32_t pr = pack2h(v[a * 4 + 2 * c], v[a * 4 + 2 * c + 1]);             \
        houtP[((size_t)((MB) * 16 + kg * 4 + a) * 4 + 2 * l5 + c) * 32 + l31] =   \
            pr;                                                                   \
      }                                                                           \
    }                                                                             \
    _Pragma("unroll") for (int r = 0; r < 16; ++r) {                              \
      float x = v[r];                                                             \
      x += __shfl_xor(x, 1); x += __shfl_xor(x, 2);                               \
      x += __shfl_xor(x, 4); x += __shfl_xor(x, 8);                               \
      x += __shfl_xor(x, 16);                                                     \
      v[r] = x;                                                                   \
    }                                                                             \
    if (kg * 32 >= klo && (lane == 0 || lane == 32)) {                            \
      float* ob = outp + (size_t)(MB) * 512 + obase + kg * 32 - klo + l5 * 4;     \
      _Pragma("unroll") for (int a = 0; a < 4; ++a)                               \
          *(f32x4*)(ob + a * 8) =                                                 \
              (f32x4){v[a * 4], v[a * 4 + 1], v[a * 4 + 2], v[a * 4 + 3]};        \
    }                                                                             \
  }

  EPILOG(accA, mb0)
  EPILOG(accB, mb0 + 1)
#undef EPILOG
}

// ---------------------------------------------------------------------------
extern "C" void kernel_launch(void* const* d_in, const int* in_sizes, int n_in,
                              void* d_out, int out_size, void* d_ws, size_t ws_size,
                              hipStream_t stream) {
  const float* feat = (const float*)d_in[0];
  const float* W0 = (const float*)d_in[1];
  const float* b0 = (const float*)d_in[2];
  const float* W1 = (const float*)d_in[3];
  const float* b1 = (const float*)d_in[4];
  const float* W2 = (const float*)d_in[5];
  const float* b2 = (const float*)d_in[6];
  float* out = (float*)d_out;
  char* ws = (char*)d_ws;

  // workspace layout (bytes)
  uint16_t* Wt0 = (uint16_t*)(ws + 0x000000);  // 512KB
  uint16_t* Wt1 = (uint16_t*)(ws + 0x080000);  // 2MB
  uint16_t* Wt2 = (uint16_t*)(ws + 0x280000);  // 2MB
  uint16_t* F16 = (uint16_t*)(ws + 0x480000);  // 1MB
  uint32_t* hP0 = (uint32_t*)(ws + 0x580000);  // [512][4][4][32]  u32 = 1MB
  uint32_t* hP1 = (uint32_t*)(ws + 0x680000);  // [512][16][4][32] u32 = 4MB
  uint32_t* hP2 = (uint32_t*)(ws + 0xA80000);  // 4MB (end 14.5MB)

  prep_kernel<<<1216, 256, 0, stream>>>(W0, W1, W2, feat, Wt0, Wt1, Wt2, F16, hP0);

  // layers: out cols [0,128)=L0 k>=128, [128,256)=L1 k>=128, [256,512)=L2 all k
  gemm_cin<32><<<512, 256, 0, stream>>>(hP0, Wt0, F16, b0, hP1, out, 0, 128);
  gemm_cin<128><<<512, 256, 0, stream>>>(hP1, Wt1, F16, b1, hP2, out, 128, 128);
  gemm_cin<128><<<512, 256, 0, stream>>>(hP2, Wt2, F16, b2, (uint32_t*)nullptr,
                                         out, 256, 0);
}

// Round 16
// 103.412 us; speedup vs baseline: 1.0411x; 1.0302x over previous
//
#include <hip/hip_runtime.h>
#include <hip/hip_fp16.h>
#include <stdint.h>

// ---------------------------------------------------------------------------
// CIN block: 3 layers of out[b,k,d] = relu(sum_ij h[b,i,d] feat[b,j,d] W[k,i,j] + b[k])
// GEMM view: m=(b,d), Out[k,m] = sum_i W[k,i,:] @ (diag(h[:,i]) F)[:,m]
// R15: LDS-BW-aware restructure. ds_read_b128 ~85B/cyc/CU caps one-LDS-operand
// MFMA at ~35% when each frag feeds only 2 MFMAs (R5-R14). Now:
//   16x16x32 MFMA, wave = 128m x 16k -> 8 independent acc chains (spacing 8),
//   each W-frag (A) feeds 8 MFMAs; B built in-register (ff[8] x broadcast h).
//   Per chunk (4 i) per wave: 4 A ds_reads + 4 h broadcast reads per 32 MFMA
//   => ~55 B/cyc/CU LDS demand (2.3x under ceiling). VALU ~half of MFMA.
// Block 256 thr (4 kw waves) = 128m x 64k; grid 512 = 128 mgrp x 4 kq
// (bx&3=kq -> per-XCD W slice 0.5MB L2-resident); 2 blocks/CU.
// W 2x16KB ping-pong + h 2x1KB, staged by global_load_lds one chunk ahead;
// boundary = vmcnt(0)+barrier (issued a full chunk earlier -> cheap).
// h in [i][l15][8 mt] u16 form: per-i h-read = ONE broadcast ds_read_b128.
// ---------------------------------------------------------------------------

typedef _Float16 half8_t __attribute__((ext_vector_type(8)));
typedef float f32x4 __attribute__((ext_vector_type(4)));
typedef uint32_t u32x4 __attribute__((ext_vector_type(4)));

union H8 {
  half8_t h;
  uint32_t u[4];
  u32x4 q;
};

#define AS1 __attribute__((address_space(1)))
#define AS3 __attribute__((address_space(3)))

static __device__ __forceinline__ uint32_t pkmul(uint32_t x, uint32_t y) {
  __half2 a = __builtin_bit_cast(__half2, x);
  __half2 b = __builtin_bit_cast(__half2, y);
  __half2 r = __hmul2(a, b);
  return __builtin_bit_cast(uint32_t, r);
}

static __device__ __forceinline__ uint32_t pack2h(float a, float b) {
  __half2 r = __floats2half2_rn(a, b);
  return __builtin_bit_cast(uint32_t, r);
}

// ---- fused prep -------------------------------------------------------------
// W [k][i][j] f32 -> Wt image blocks [(i>>2)*4 + (k>>6)][16KB]:
//   byte = (i&3)*4096 + (k&63)*64 + ((jg ^ (((k&63)>>1)&3))<<4)
// blocks [0,128): W0 ; [128,640): W1 ; [640,1152): W2
// blocks [1152,1216): feat -> F16 [m][32 j] f16 and hW0 [i][mgrp][16 l15][8 mt]
__global__ void prep_kernel(const float* __restrict__ W0, const float* __restrict__ W1,
                            const float* __restrict__ W2, const float* __restrict__ feat,
                            uint16_t* __restrict__ Wt0, uint16_t* __restrict__ Wt1,
                            uint16_t* __restrict__ Wt2,
                            uint16_t* __restrict__ F16, uint16_t* __restrict__ hW0) {
  int blk = blockIdx.x;
  if (blk < 1152) {
    const float* W; uint16_t* Wt; int FLsh, base;
    if (blk < 128)      { W = W0; Wt = Wt0; FLsh = 5; base = 0; }
    else if (blk < 640) { W = W1; Wt = Wt1; FLsh = 7; base = 128; }
    else                { W = W2; Wt = Wt2; FLsh = 7; base = 640; }
    int idx4 = (blk - base) * 256 + threadIdx.x;
    int jg = idx4 & 3;
    int i = (idx4 >> 2) & ((1 << FLsh) - 1);
    int k = idx4 >> (2 + FLsh);
    const float* src = W + ((size_t)(k << FLsh) + i) * 32 + jg * 8;
    float4 x0 = *(const float4*)(src);
    float4 x1 = *(const float4*)(src + 4);
    u32x4 o;
    o[0] = pack2h(x0.x, x0.y);
    o[1] = pack2h(x0.z, x0.w);
    o[2] = pack2h(x1.x, x1.y);
    o[3] = pack2h(x1.z, x1.w);
    int q = i >> 2, il = i & 3, kq = k >> 6, kl = k & 63;
    int slot = jg ^ ((kl >> 1) & 3);
    size_t byteoff = (size_t)(q * 4 + kq) * 16384 + il * 4096 + kl * 64 + (slot << 4);
    *(u32x4*)((char*)Wt + byteoff) = o;
  } else {
    int m = (blk - 1152) * 256 + threadIdx.x;  // 0..16383
    int b = m >> 5, d = m & 31;
    const float* fb = feat + (size_t)b * 1024 + d;
    uint16_t hs[32];
#pragma unroll
    for (int j = 0; j < 32; ++j)
      hs[j] = __half_as_ushort(__float2half(fb[j * 32]));
    // hW0 [i][mgrp][16 l15][8 mt] u16
    int mgrp = m >> 7, l15 = m & 15, mt = (m >> 4) & 7;
#pragma unroll
    for (int j = 0; j < 32; ++j)
      hW0[((size_t)j * 128 + mgrp) * 128 + l15 * 8 + mt] = hs[j];
#pragma unroll
    for (int c = 0; c < 4; ++c) {
      u32x4 qv;
      qv[0] = (uint32_t)hs[c * 8 + 0] | ((uint32_t)hs[c * 8 + 1] << 16);
      qv[1] = (uint32_t)hs[c * 8 + 2] | ((uint32_t)hs[c * 8 + 3] << 16);
      qv[2] = (uint32_t)hs[c * 8 + 4] | ((uint32_t)hs[c * 8 + 5] << 16);
      qv[3] = (uint32_t)hs[c * 8 + 6] | ((uint32_t)hs[c * 8 + 7] << 16);
      *(u32x4*)(F16 + (size_t)m * 32 + c * 8) = qv;
    }
  }
}

// ---- fused CIN layer GEMM ---------------------------------------------------
// grid 512: bx = mgrp*4 + kq. Block 256 thr (4 waves = kw); wave = 128m x 16k.
template <int FL>
__global__ __launch_bounds__(256, 2) void gemm_cin(
    const uint16_t* __restrict__ hW,    // [FL][128 mgrp][16][8] u16
    const uint16_t* __restrict__ wt,    // [(FL/4) q][4 kq][16KB] images
    const uint16_t* __restrict__ f16m,  // [16384][32] f16
    const float* __restrict__ bias,     // [256]
    uint16_t* __restrict__ hWn,         // [128][128][16][8] u16, or null
    float* __restrict__ outp,           // [512][512] f32
    int obase, int klo) {
  constexpr int NCHK = FL / 4;
  constexpr int NCM = NCHK - 1;
  __shared__ __align__(16) char smem[34816];  // W 2x16KB @0 ; h 2x1KB @32768
  const int tid = threadIdx.x;
  const int lane = tid & 63, w = tid >> 6;  // w = kw
  const int l15 = lane & 15, lq = lane >> 4;
  const int kq = blockIdx.x & 3, mgrp = blockIdx.x >> 2;
  const int m0g = mgrp * 128, k0g = kq * 64;

  // --- resident F fragments: ff[mt] = F[m0g + mt*16 + l15][lq*8 .. +8] ---
  H8 ff[8];
#pragma unroll
  for (int mt = 0; mt < 8; ++mt)
    ff[mt].q = *(const u32x4*)(f16m + (size_t)(m0g + mt * 16 + l15) * 32 + lq * 8);

  // --- staging bases ---
  const char* wsrc = (const char*)wt + kq * 16384 + tid * 16;
  char* wdst = smem + tid * 16;
  const char* hsrc = (const char*)hW + (size_t)mgrp * 256 + (tid & 15) * 16 +
                     (size_t)(tid >> 4) * 32768;
  char* hdst = smem + 32768 + (tid >> 4) * 256 + (tid & 15) * 16;

#define STAGE(QQ, PAR)                                                        \
  { size_t qo_ = (size_t)((QQ) & NCM);                                        \
    const char* s_ = wsrc + qo_ * 65536;                                      \
    char* d_ = wdst + (PAR) * 16384;                                          \
    _Pragma("unroll") for (int c_ = 0; c_ < 4; ++c_)                          \
      __builtin_amdgcn_global_load_lds((const AS1 uint32_t*)(s_ + c_ * 4096), \
                                       (AS3 uint32_t*)(d_ + c_ * 4096), 16, 0, 0); \
    if (tid < 64)                                                             \
      __builtin_amdgcn_global_load_lds(                                       \
          (const AS1 uint32_t*)(hsrc + qo_ * 131072),                         \
          (AS3 uint32_t*)(hdst + (PAR) * 1024), 16, 0, 0); }

  // --- per-lane read bases (2-way-max bank aliasing by XOR swizzle) ---
  const char* arb = smem + (w * 16 + l15) * 64 + ((lq ^ ((l15 >> 1) & 3)) << 4);
  const char* hrb = smem + 32768 + l15 * 16;  // lq-dup -> broadcast

  f32x4 acc[8];
#pragma unroll
  for (int mt = 0; mt < 8; ++mt) acc[mt] = (f32x4){0.f, 0.f, 0.f, 0.f};

  STAGE(0, 0)
  asm volatile("s_waitcnt vmcnt(0)" ::: "memory");
  __builtin_amdgcn_s_barrier();

  // one i-step: 8 B-frags built in-register, then 8 contiguous MFMA (8 chains)
#define ISTEP(AI, HI)                                                              \
  { H8 b0_, b1_, b2_, b3_, b4_, b5_, b6_, b7_;                                     \
    uint32_t hd_;                                                                  \
    hd_ = __builtin_amdgcn_perm(HI.u[0], HI.u[0], 0x01000100u);                    \
    _Pragma("unroll") for (int c_ = 0; c_ < 4; ++c_) b0_.u[c_] = pkmul(ff[0].u[c_], hd_); \
    hd_ = __builtin_amdgcn_perm(HI.u[0], HI.u[0], 0x03020302u);                    \
    _Pragma("unroll") for (int c_ = 0; c_ < 4; ++c_) b1_.u[c_] = pkmul(ff[1].u[c_], hd_); \
    hd_ = __builtin_amdgcn_perm(HI.u[1], HI.u[1], 0x01000100u);                    \
    _Pragma("unroll") for (int c_ = 0; c_ < 4; ++c_) b2_.u[c_] = pkmul(ff[2].u[c_], hd_); \
    hd_ = __builtin_amdgcn_perm(HI.u[1], HI.u[1], 0x03020302u);                    \
    _Pragma("unroll") for (int c_ = 0; c_ < 4; ++c_) b3_.u[c_] = pkmul(ff[3].u[c_], hd_); \
    hd_ = __builtin_amdgcn_perm(HI.u[2], HI.u[2], 0x01000100u);                    \
    _Pragma("unroll") for (int c_ = 0; c_ < 4; ++c_) b4_.u[c_] = pkmul(ff[4].u[c_], hd_); \
    hd_ = __builtin_amdgcn_perm(HI.u[2], HI.u[2], 0x03020302u);                    \
    _Pragma("unroll") for (int c_ = 0; c_ < 4; ++c_) b5_.u[c_] = pkmul(ff[5].u[c_], hd_); \
    hd_ = __builtin_amdgcn_perm(HI.u[3], HI.u[3], 0x01000100u);                    \
    _Pragma("unroll") for (int c_ = 0; c_ < 4; ++c_) b6_.u[c_] = pkmul(ff[6].u[c_], hd_); \
    hd_ = __builtin_amdgcn_perm(HI.u[3], HI.u[3], 0x03020302u);                    \
    _Pragma("unroll") for (int c_ = 0; c_ < 4; ++c_) b7_.u[c_] = pkmul(ff[7].u[c_], hd_); \
    __builtin_amdgcn_s_setprio(1);                                                 \
    acc[0] = __builtin_amdgcn_mfma_f32_16x16x32_f16(AI.h, b0_.h, acc[0], 0, 0, 0); \
    acc[1] = __builtin_amdgcn_mfma_f32_16x16x32_f16(AI.h, b1_.h, acc[1], 0, 0, 0); \
    acc[2] = __builtin_amdgcn_mfma_f32_16x16x32_f16(AI.h, b2_.h, acc[2], 0, 0, 0); \
    acc[3] = __builtin_amdgcn_mfma_f32_16x16x32_f16(AI.h, b3_.h, acc[3], 0, 0, 0); \
    acc[4] = __builtin_amdgcn_mfma_f32_16x16x32_f16(AI.h, b4_.h, acc[4], 0, 0, 0); \
    acc[5] = __builtin_amdgcn_mfma_f32_16x16x32_f16(AI.h, b5_.h, acc[5], 0, 0, 0); \
    acc[6] = __builtin_amdgcn_mfma_f32_16x16x32_f16(AI.h, b6_.h, acc[6], 0, 0, 0); \
    acc[7] = __builtin_amdgcn_mfma_f32_16x16x32_f16(AI.h, b7_.h, acc[7], 0, 0, 0); \
    __builtin_amdgcn_s_setprio(0); }

#pragma unroll 1
  for (int q = 0; q < NCHK; ++q) {
    const int par = q & 1;
    const char* ab = arb + par * 16384;
    const char* hb = hrb + par * 1024;
    H8 a0, a1, a2, a3, h0, h1, h2, h3;
    a0.q = *(const u32x4*)(ab);
    a1.q = *(const u32x4*)(ab + 4096);
    a2.q = *(const u32x4*)(ab + 8192);
    a3.q = *(const u32x4*)(ab + 12288);
    h0.q = *(const u32x4*)(hb);
    h1.q = *(const u32x4*)(hb + 256);
    h2.q = *(const u32x4*)(hb + 512);
    h3.q = *(const u32x4*)(hb + 768);
    STAGE(q + 1, par ^ 1)
    ISTEP(a0, h0)
    ISTEP(a1, h1)
    ISTEP(a2, h2)
    ISTEP(a3, h3)
    asm volatile("s_waitcnt vmcnt(0)" ::: "memory");
    __builtin_amdgcn_s_barrier();
  }
#undef ISTEP
#undef STAGE

  // ---- epilogue: bias + relu; C row k = k0g + w*16 + lq*4 + r, col m = l15 --
  f32x4 bv = *(const f32x4*)(bias + k0g + w * 16 + lq * 4);
  float v[8][4];
#pragma unroll
  for (int mt = 0; mt < 8; ++mt)
#pragma unroll
    for (int r = 0; r < 4; ++r) {
      float x = acc[mt][r] + bv[r];
      v[mt][r] = x > 0.f ? x : 0.f;
    }

  // ---- h for next layer (k < 128 -> kq < 2) ---------------------------------
  if (hWn != nullptr && kq < 2) {
#pragma unroll
    for (int mt = 0; mt < 8; ++mt)
#pragma unroll
      for (int r = 0; r < 4; ++r) {
        int k = k0g + w * 16 + lq * 4 + r;
        hWn[((size_t)k * 128 + mgrp) * 128 + l15 * 8 + mt] =
            __half_as_ushort(__float2half(v[mt][r]));
      }
  }

  // ---- d-reduction -> output (4 b-rows per wave) -----------------------------
#pragma unroll
  for (int p = 0; p < 4; ++p) {
    f32x4 sv;
#pragma unroll
    for (int r = 0; r < 4; ++r) {
      float x = v[2 * p][r] + v[2 * p + 1][r];
      x += __shfl_xor(x, 1);
      x += __shfl_xor(x, 2);
      x += __shfl_xor(x, 4);
      x += __shfl_xor(x, 8);
      sv[r] = x;
    }
    if (l15 == 0 && k0g >= klo) {
      float* ob = outp + (size_t)(mgrp * 4 + p) * 512 + obase + k0g + w * 16 +
                  lq * 4 - klo;
      *(f32x4*)ob = sv;
    }
  }
}

// ---------------------------------------------------------------------------
extern "C" void kernel_launch(void* const* d_in, const int* in_sizes, int n_in,
                              void* d_out, int out_size, void* d_ws, size_t ws_size,
                              hipStream_t stream) {
  const float* feat = (const float*)d_in[0];
  const float* W0 = (const float*)d_in[1];
  const float* b0 = (const float*)d_in[2];
  const float* W1 = (const float*)d_in[3];
  const float* b1 = (const float*)d_in[4];
  const float* W2 = (const float*)d_in[5];
  const float* b2 = (const float*)d_in[6];
  float* out = (float*)d_out;
  char* ws = (char*)d_ws;

  // workspace layout (bytes)
  uint16_t* Wt0 = (uint16_t*)(ws + 0x000000);  // 512KB
  uint16_t* Wt1 = (uint16_t*)(ws + 0x080000);  // 2MB
  uint16_t* Wt2 = (uint16_t*)(ws + 0x280000);  // 2MB
  uint16_t* F16 = (uint16_t*)(ws + 0x480000);  // 1MB
  uint16_t* hW0 = (uint16_t*)(ws + 0x580000);  // [32][128][16][8]  u16 = 1MB
  uint16_t* hW1 = (uint16_t*)(ws + 0x680000);  // [128][128][16][8] u16 = 4MB
  uint16_t* hW2 = (uint16_t*)(ws + 0xA80000);  // 4MB (end 14.5MB)

  prep_kernel<<<1216, 256, 0, stream>>>(W0, W1, W2, feat, Wt0, Wt1, Wt2, F16, hW0);

  // layers: out cols [0,128)=L0 k>=128, [128,256)=L1 k>=128, [256,512)=L2 all k
  gemm_cin<32><<<512, 256, 0, stream>>>(hW0, Wt0, F16, b0, hW1, out, 0, 128);
  gemm_cin<128><<<512, 256, 0, stream>>>(hW1, Wt1, F16, b1, hW2, out, 128, 128);
  gemm_cin<128><<<512, 256, 0, stream>>>(hW2, Wt2, F16, b2, (uint16_t*)nullptr,
                                         out, 256, 0);
}

// Round 17
// 98.386 us; speedup vs baseline: 1.0943x; 1.0511x over previous
//
#include <hip/hip_runtime.h>
#include <hip/hip_fp16.h>
#include <stdint.h>

// ---------------------------------------------------------------------------
// CIN block: 3 layers of out[b,k,d] = relu(sum_ij h[b,i,d] feat[b,j,d] W[k,i,j] + b[k])
// GEMM view: m=(b,d), Out[k,m] = sum_i W[k,i,:] @ (diag(h[:,i]) F)[:,m]
// R16: density + TLP. Wave = 16m x 64k, 16x16x32 MFMA:
//   per i-step: ONE B-frag (4 pkmul, h pre-dup'd -> 0 perm) feeds 4 MFMA
//   (4 k-tiles), W via 4 ds_read_b128 -> 1 VALU + 1 ds per MFMA.
// 4096 waves total = 16 waves/CU = 4/SIMD (vs 2 in R5-R15).
// Block 512 thr (8 waves = 8 mb16), grid 512 = 128 mgrp x 4 kq, 2 blocks/CU.
// W: R15's image format + XOR swizzle (0 conflicts, proven); 2x32KB dbuf,
// staged 1 chunk (8 i) ahead; boundary vmcnt(0)+barrier (chunk-old, cheap).
// h: global dup-pair stream [mb16][i4][16][4], one u32x4 per 4-i, prefetched.
// Epilogue: bias+relu; h-out as coalesced b128 dup-pairs; d-reduce = shfl
// over l15 + cross-wave-pair psum in LDS (2KB) + 1 barrier.
// ---------------------------------------------------------------------------

typedef _Float16 half8_t __attribute__((ext_vector_type(8)));
typedef float f32x4 __attribute__((ext_vector_type(4)));
typedef uint32_t u32x4 __attribute__((ext_vector_type(4)));

union H8 {
  half8_t h;
  uint32_t u[4];
  u32x4 q;
};

#define AS1 __attribute__((address_space(1)))
#define AS3 __attribute__((address_space(3)))

static __device__ __forceinline__ uint32_t pkmul(uint32_t x, uint32_t y) {
  __half2 a = __builtin_bit_cast(__half2, x);
  __half2 b = __builtin_bit_cast(__half2, y);
  __half2 r = __hmul2(a, b);
  return __builtin_bit_cast(uint32_t, r);
}

static __device__ __forceinline__ uint32_t dup2h(float a) {
  return (uint32_t)__half_as_ushort(__float2half(a)) * 0x10001u;
}

static __device__ __forceinline__ uint32_t pack2h(float a, float b) {
  __half2 r = __floats2half2_rn(a, b);
  return __builtin_bit_cast(uint32_t, r);
}

// ---- fused prep -------------------------------------------------------------
// W [k][i][j] f32 -> Wt image blocks [(i>>2)*4 + (k>>6)][16KB]:
//   byte = (i&3)*4096 + (k&63)*64 + ((jg ^ (((k&63)>>1)&3))<<4)   (R15 format)
// blocks [0,128): W0 ; [128,640): W1 ; [640,1152): W2
// blocks [1152,1216): feat -> F16 [m][32 j] f16, hd0 [mb16][8 i4][16][4] u32
__global__ void prep_kernel(const float* __restrict__ W0, const float* __restrict__ W1,
                            const float* __restrict__ W2, const float* __restrict__ feat,
                            uint16_t* __restrict__ Wt0, uint16_t* __restrict__ Wt1,
                            uint16_t* __restrict__ Wt2,
                            uint16_t* __restrict__ F16, uint32_t* __restrict__ hd0) {
  int blk = blockIdx.x;
  if (blk < 1152) {
    const float* W; uint16_t* Wt; int FLsh, base;
    if (blk < 128)      { W = W0; Wt = Wt0; FLsh = 5; base = 0; }
    else if (blk < 640) { W = W1; Wt = Wt1; FLsh = 7; base = 128; }
    else                { W = W2; Wt = Wt2; FLsh = 7; base = 640; }
    int idx4 = (blk - base) * 256 + threadIdx.x;
    int jg = idx4 & 3;
    int i = (idx4 >> 2) & ((1 << FLsh) - 1);
    int k = idx4 >> (2 + FLsh);
    const float* src = W + ((size_t)(k << FLsh) + i) * 32 + jg * 8;
    float4 x0 = *(const float4*)(src);
    float4 x1 = *(const float4*)(src + 4);
    u32x4 o;
    o[0] = pack2h(x0.x, x0.y);
    o[1] = pack2h(x0.z, x0.w);
    o[2] = pack2h(x1.x, x1.y);
    o[3] = pack2h(x1.z, x1.w);
    int q = i >> 2, il = i & 3, kq = k >> 6, kl = k & 63;
    int slot = jg ^ ((kl >> 1) & 3);
    size_t byteoff = (size_t)(q * 4 + kq) * 16384 + il * 4096 + kl * 64 + (slot << 4);
    *(u32x4*)((char*)Wt + byteoff) = o;
  } else {
    int m = (blk - 1152) * 256 + threadIdx.x;  // 0..16383
    int b = m >> 5, d = m & 31;
    const float* fb = feat + (size_t)b * 1024 + d;
    uint16_t hs[32];
#pragma unroll
    for (int j = 0; j < 32; ++j)
      hs[j] = __half_as_ushort(__float2half(fb[j * 32]));
    // hd0 [mb16][i>>2][l15][i&3] u32 dup-pairs
    int mb16 = m >> 4, l15 = m & 15;
#pragma unroll
    for (int i = 0; i < 32; ++i)
      hd0[((size_t)(mb16 * 8 + (i >> 2)) * 16 + l15) * 4 + (i & 3)] =
          (uint32_t)hs[i] * 0x10001u;
#pragma unroll
    for (int c = 0; c < 4; ++c) {
      u32x4 qv;
      qv[0] = (uint32_t)hs[c * 8 + 0] | ((uint32_t)hs[c * 8 + 1] << 16);
      qv[1] = (uint32_t)hs[c * 8 + 2] | ((uint32_t)hs[c * 8 + 3] << 16);
      qv[2] = (uint32_t)hs[c * 8 + 4] | ((uint32_t)hs[c * 8 + 5] << 16);
      qv[3] = (uint32_t)hs[c * 8 + 6] | ((uint32_t)hs[c * 8 + 7] << 16);
      *(u32x4*)(F16 + (size_t)m * 32 + c * 8) = qv;
    }
  }
}

// ---- fused CIN layer GEMM ---------------------------------------------------
// grid 512: bx = mgrp*4 + kq. Block 512 thr (8 waves); wave w: mb16 = mgrp*8+w,
// tile 16m x 64k (4 kt chains), full K. 16x16x32 MFMA, 1 VALU + 1 ds per MFMA.
template <int FL>
__global__ __launch_bounds__(512, 4) void gemm_cin(
    const uint32_t* __restrict__ hdup,  // [mb16][FL/4][16][4] u32 dup-pairs
    const uint16_t* __restrict__ wt,    // [(FL/4) q][4 kq][16KB] images
    const uint16_t* __restrict__ f16m,  // [16384][32] f16
    const float* __restrict__ bias,     // [256]
    uint32_t* __restrict__ hdn,         // [mb16][32][16][4] u32, or null
    float* __restrict__ outp,           // [512][512] f32
    int obase, int klo) {
  constexpr int NCHK = FL / 8;
  constexpr int NCM = NCHK - 1;
  __shared__ __align__(16) char smem[67584];  // 2x32KB W dbuf + 2KB psum
  const int tid = threadIdx.x;
  const int lane = tid & 63, w = tid >> 6;
  const int l15 = lane & 15, lq = lane >> 4;
  const int kq = blockIdx.x & 3, mgrp = blockIdx.x >> 2;
  const int mb16 = mgrp * 8 + w;

  // --- resident F fragment: ff = F[mb16*16 + l15][lq*8 .. +8] ---
  H8 ff;
  ff.q = *(const u32x4*)(f16m + (size_t)(mb16 * 16 + l15) * 32 + lq * 8);

  // --- W staging (R15 image format) ---
  const char* wbase = (const char*)wt + kq * 16384;

#define STAGE(CN, PAR)                                                        \
  { _Pragma("unroll") for (int im_ = 0; im_ < 2; ++im_) {                     \
      const char* s_ = wbase + (size_t)((2 * (CN) + im_) * 4) * 16384 + tid * 16; \
      char* d_ = smem + (PAR) * 32768 + im_ * 16384 + tid * 16;               \
      __builtin_amdgcn_global_load_lds((const AS1 uint32_t*)(s_),             \
                                       (AS3 uint32_t*)(d_), 16, 0, 0);        \
      __builtin_amdgcn_global_load_lds((const AS1 uint32_t*)(s_ + 8192),      \
                                       (AS3 uint32_t*)(d_ + 8192), 16, 0, 0); \
    } }

  // --- h dup-pair stream (global -> regs, one u32x4 per 4 i) ---
  const char* hsrc = (const char*)hdup + (size_t)mb16 * (FL / 4) * 256 + l15 * 16;

#define HLD(CN, D0, D1)                                                       \
  { const char* p_ = hsrc + (size_t)(2 * (CN)) * 256;                         \
    D0 = *(const u32x4*)(p_);                                                 \
    D1 = *(const u32x4*)(p_ + 256); }

  u32x4 hc0, hc1, hn0, hn1;

  STAGE(0, 0)
  HLD(0, hc0, hc1)

  f32x4 acc0 = {0.f, 0.f, 0.f, 0.f}, acc1 = acc0, acc2 = acc0, acc3 = acc0;
  const char* rlane = smem + l15 * 64 + ((lq ^ ((l15 >> 1) & 3)) << 4);

  asm volatile("s_waitcnt vmcnt(0)" ::: "memory");
  __builtin_amdgcn_s_barrier();

  // one i-step: 4 W ds_reads + 4 pkmul (one B-frag) + 4 MFMA (4 kt chains)
#define ISTEP(PAR, G, II, HV)                                                      \
  { const char* rb_ = rlane + (PAR) * 32768 + (G) * 16384 + (II) * 4096;           \
    H8 w0_, w1_, w2_, w3_, b_;                                                     \
    w0_.q = *(const u32x4*)(rb_);                                                  \
    w1_.q = *(const u32x4*)(rb_ + 1024);                                           \
    w2_.q = *(const u32x4*)(rb_ + 2048);                                           \
    w3_.q = *(const u32x4*)(rb_ + 3072);                                           \
    uint32_t hv_ = (HV);                                                           \
    H8 b2_;                                                                        \
    _Pragma("unroll") for (int c_ = 0; c_ < 4; ++c_) b2_.u[c_] = pkmul(ff.u[c_], hv_); \
    b_ = b2_;                                                                      \
    acc0 = __builtin_amdgcn_mfma_f32_16x16x32_f16(w0_.h, b_.h, acc0, 0, 0, 0);     \
    acc1 = __builtin_amdgcn_mfma_f32_16x16x32_f16(w1_.h, b_.h, acc1, 0, 0, 0);     \
    acc2 = __builtin_amdgcn_mfma_f32_16x16x32_f16(w2_.h, b_.h, acc2, 0, 0, 0);     \
    acc3 = __builtin_amdgcn_mfma_f32_16x16x32_f16(w3_.h, b_.h, acc3, 0, 0, 0); }

#pragma unroll 1
  for (int c = 0; c < NCHK; ++c) {
    const int par = c & 1;
    STAGE((c + 1) & NCM, par ^ 1)
    HLD((c + 1) & NCM, hn0, hn1)
    ISTEP(par, 0, 0, hc0[0])
    ISTEP(par, 0, 1, hc0[1])
    ISTEP(par, 0, 2, hc0[2])
    ISTEP(par, 0, 3, hc0[3])
    ISTEP(par, 1, 0, hc1[0])
    ISTEP(par, 1, 1, hc1[1])
    ISTEP(par, 1, 2, hc1[2])
    ISTEP(par, 1, 3, hc1[3])
    hc0 = hn0;
    hc1 = hn1;
    asm volatile("s_waitcnt vmcnt(0)" ::: "memory");
    __builtin_amdgcn_s_barrier();
  }
#undef ISTEP
#undef STAGE
#undef HLD

  // ---- epilogue: bias + relu; acc[kt][r]: k = kq*64 + kt*16 + lq*4 + r ------
  float v[4][4];
  {
    f32x4 aq[4] = {acc0, acc1, acc2, acc3};
#pragma unroll
    for (int kt = 0; kt < 4; ++kt) {
      f32x4 bv = *(const f32x4*)(bias + kq * 64 + kt * 16 + lq * 4);
#pragma unroll
      for (int r = 0; r < 4; ++r) {
        float x = aq[kt][r] + bv[r];
        v[kt][r] = x > 0.f ? x : 0.f;
      }
    }
  }

  // ---- h for next layer (k < 128 -> kq < 2), coalesced b128 dup-pairs -------
  if (hdn != nullptr && kq < 2) {
#pragma unroll
    for (int kt = 0; kt < 4; ++kt) {
      int i4 = kq * 16 + kt * 4 + lq;  // i = i4*4 + r
      u32x4 du;
#pragma unroll
      for (int r = 0; r < 4; ++r) du[r] = dup2h(v[kt][r]);
      *(u32x4*)((char*)hdn + ((size_t)(mb16 * 32 + i4) * 16 + l15) * 16) = du;
    }
  }

  // ---- d-reduction: shfl over l15 (16 d's), then cross-wave-pair via LDS ----
  float* psum = (float*)(smem + 65536);
#pragma unroll
  for (int kt = 0; kt < 4; ++kt)
#pragma unroll
    for (int r = 0; r < 4; ++r) {
      float x = v[kt][r];
      x += __shfl_xor(x, 1);
      x += __shfl_xor(x, 2);
      x += __shfl_xor(x, 4);
      x += __shfl_xor(x, 8);
      v[kt][r] = x;
    }
  if (l15 == 0) {
#pragma unroll
    for (int kt = 0; kt < 4; ++kt)
#pragma unroll
      for (int r = 0; r < 4; ++r)
        psum[w * 64 + kt * 16 + lq * 4 + r] = v[kt][r];
  }
  __builtin_amdgcn_s_barrier();
  if ((w & 1) == 0) {
    int b = mgrp * 4 + (w >> 1);
    float s = psum[w * 64 + lane] + psum[(w + 1) * 64 + lane];
    int k = kq * 64 + lane;
    if (k >= klo) outp[(size_t)b * 512 + obase + k - klo] = s;
  }
}

// ---------------------------------------------------------------------------
extern "C" void kernel_launch(void* const* d_in, const int* in_sizes, int n_in,
                              void* d_out, int out_size, void* d_ws, size_t ws_size,
                              hipStream_t stream) {
  const float* feat = (const float*)d_in[0];
  const float* W0 = (const float*)d_in[1];
  const float* b0 = (const float*)d_in[2];
  const float* W1 = (const float*)d_in[3];
  const float* b1 = (const float*)d_in[4];
  const float* W2 = (const float*)d_in[5];
  const float* b2 = (const float*)d_in[6];
  float* out = (float*)d_out;
  char* ws = (char*)d_ws;

  // workspace layout (bytes)
  uint16_t* Wt0 = (uint16_t*)(ws + 0x000000);  // 512KB
  uint16_t* Wt1 = (uint16_t*)(ws + 0x080000);  // 2MB
  uint16_t* Wt2 = (uint16_t*)(ws + 0x280000);  // 2MB
  uint16_t* F16 = (uint16_t*)(ws + 0x480000);  // 1MB
  uint32_t* hd0 = (uint32_t*)(ws + 0x580000);  // [1024][8][16][4]u32  = 2MB
  uint32_t* hd1 = (uint32_t*)(ws + 0x780000);  // [1024][32][16][4]u32 = 8MB
  uint32_t* hd2 = (uint32_t*)(ws + 0xF80000);  // 8MB (end 23.5MB)

  prep_kernel<<<1216, 256, 0, stream>>>(W0, W1, W2, feat, Wt0, Wt1, Wt2, F16, hd0);

  // layers: out cols [0,128)=L0 k>=128, [128,256)=L1 k>=128, [256,512)=L2 all k
  gemm_cin<32><<<512, 512, 0, stream>>>(hd0, Wt0, F16, b0, hd1, out, 0, 128);
  gemm_cin<128><<<512, 512, 0, stream>>>(hd1, Wt1, F16, b1, hd2, out, 128, 128);
  gemm_cin<128><<<512, 512, 0, stream>>>(hd2, Wt2, F16, b2, (uint32_t*)nullptr,
                                         out, 256, 0);
}